// Round 2
// baseline (204.683 us; speedup 1.0000x reference)
//
#include <hip/hip_runtime.h>
#include <hip/hip_bf16.h>
#include <stdint.h>
#include <stddef.h>

#define T_LEN   2048
#define C_IN_   512
#define D_MODEL_ 1024
#define B_SZ    32

typedef __hip_bfloat16 bf16;
typedef __attribute__((ext_vector_type(8))) short short8;
typedef __attribute__((ext_vector_type(4))) float f32x4;

// ---------------------------------------------------------------------------
// async global->LDS, 16B per lane (linear dest: wave-uniform base + lane*16)
// ---------------------------------------------------------------------------
__device__ __forceinline__ void gload16(const void* g, void* l) {
    __builtin_amdgcn_global_load_lds(
        (const __attribute__((address_space(1))) uint32_t*)g,
        (__attribute__((address_space(3))) uint32_t*)l, 16, 0, 0);
}

// ---------------------------------------------------------------------------
// Kernel 1: W (fp32 [1024][512]) -> bf16, same layout
// ---------------------------------------------------------------------------
__global__ void wconv_kernel(const float* __restrict__ W, bf16* __restrict__ Wb) {
    int i = blockIdx.x * 256 + threadIdx.x;       // 131072 float4 units
    float4 v = ((const float4*)W)[i];
    bf16* o = Wb + (size_t)i * 4;
    o[0] = __float2bfloat16(v.x);
    o[1] = __float2bfloat16(v.y);
    o[2] = __float2bfloat16(v.z);
    o[3] = __float2bfloat16(v.w);
}

// ---------------------------------------------------------------------------
// Kernel 2: bidirectional EWMA, exact 3-level scan, output bf16 A[M=b*T+t][c]
// 512 threads = 8 waves; wave = 2 rows (b,c); lane&31 = 64-t chunk index.
// __launch_bounds__(512) -> VGPR budget 256, xr[64] fits with NO spills
// (the 1024-thread version capped at 128 VGPR and likely spilled xr).
// ---------------------------------------------------------------------------
__global__ __launch_bounds__(512)
void ewma_kernel(const float* __restrict__ x, bf16* __restrict__ A) {
    const int tid  = threadIdx.x;
    const int wid  = tid >> 6;          // 0..7
    const int lane = tid & 63;
    const int half = lane >> 5;         // 0,1 -> which row of the wave
    const int j    = lane & 31;         // chunk (64 t's each)
    const int b    = blockIdx.x >> 5;   // 0..31
    const int cg   = blockIdx.x & 31;   // 0..31 (16 channels per block)
    const int c_local = (wid << 1) | half;       // 0..15
    const int c    = (cg << 4) + c_local;

    const float AL = 0.1f, OM = 0.9f;
    const float Q  = 1.179018457773862e-3f;      // 0.9^64

    // ---- P1: load 64 consecutive x values into registers
    float xr[64];
    const float4* xp = (const float4*)(x + (size_t)(b * C_IN_ + c) * T_LEN + j * 64);
    #pragma unroll
    for (int i = 0; i < 16; ++i) {
        float4 v = xp[i];
        xr[4*i+0] = v.x; xr[4*i+1] = v.y; xr[4*i+2] = v.z; xr[4*i+3] = v.w;
    }

    // ---- P2: local fwd scan (zero carry), end value g. t=0 special: f0 = x0.
    float g = (j == 0) ? xr[0] : AL * xr[0];
    #pragma unroll
    for (int i = 1; i < 64; ++i) g = fmaf(OM, g, AL * xr[i]);

    // ---- P3: Kogge-Stone carry scan across the 32 chunks (width-32 groups)
    float F = g, coef = Q;
    #pragma unroll
    for (int d = 1; d < 32; d <<= 1) {
        float up = __shfl_up(F, d, 32);
        F += (j >= d) ? coef * up : 0.0f;
        coef *= coef;
    }
    float carry = __shfl_up(F, 1, 32);           // true f at t0-1
    if (j == 0) carry = 0.0f;

    // ---- P4: seeded fwd recompute, in place (xr becomes f)
    xr[0] = (j == 0) ? xr[0] : fmaf(OM, carry, AL * xr[0]);
    #pragma unroll
    for (int i = 1; i < 64; ++i) xr[i] = fmaf(OM, xr[i-1], AL * xr[i]);

    // ---- P5: local bwd scan built from f only: inc[t] = alpha*x_t = f[t]-0.9f[t-1]
    //          specials: t=0 -> alpha*f[0]; t=T-1 -> 10*(f-0.9f_prev) = x_{T-1}
    float h;
    {
        float incL = xr[63] - OM * xr[62];
        if (j == 31) incL *= 10.0f;
        h = incL;
        #pragma unroll
        for (int i = 62; i >= 1; --i) h = fmaf(OM, h, xr[i] - OM * xr[i-1]);
        float inc0 = (j == 0) ? AL * xr[0] : (xr[0] - OM * carry);
        h = fmaf(OM, h, inc0);
    }

    // ---- P6: bwd carry scan (toward higher j)
    float Bv = h; coef = Q;
    #pragma unroll
    for (int d = 1; d < 32; d <<= 1) {
        float dn = __shfl_down(Bv, d, 32);
        Bv += (j < 32 - d) ? coef * dn : 0.0f;
        coef *= coef;
    }
    float bnext = __shfl_down(Bv, 1, 32);        // true b at t0+64
    if (j == 31) bnext = 0.0f;

    // ---- P7: final bwd recompute + combine, in place (xr becomes 0.5*(f+b))
    {
        float bp = bnext;
        float incL = xr[63] - OM * xr[62];
        if (j == 31) incL *= 10.0f;
        float bb = fmaf(OM, bp, incL);
        xr[63] = 0.5f * (xr[63] + bb);
        bp = bb;
        #pragma unroll
        for (int i = 62; i >= 1; --i) {
            float inc = xr[i] - OM * xr[i-1];
            bb = fmaf(OM, bp, inc);
            xr[i] = 0.5f * (xr[i] + bb);
            bp = bb;
        }
        float inc0 = (j == 0) ? AL * xr[0] : (xr[0] - OM * carry);
        bb = fmaf(OM, bp, inc0);
        xr[0] = 0.5f * (xr[0] + bb);
    }

    // ---- P8: LDS transpose stage -> coalesced bf16 writes (16 ch = 32B/t-row)
    // staging elem layout [j:5][ii:4][c:4], XOR-swizzled by (j&7)<<3
    // (flips elem bits 3-5 = byte bits 4-6 -> 16B-unit-aligned, bijective)
    __shared__ bf16 stg[32 * 16 * 16];           // 16KB
    const size_t outbase = (size_t)(b * T_LEN) * C_IN_ + (cg << 4);
    #pragma unroll
    for (int grp = 0; grp < 4; ++grp) {
        __syncthreads();
        #pragma unroll
        for (int ii = 0; ii < 16; ++ii) {
            int elem = ((j * 16 + ii) * 16 + c_local) ^ ((j & 7) << 3);
            stg[elem] = __float2bfloat16(xr[grp * 16 + ii]);
        }
        __syncthreads();
        #pragma unroll
        for (int r = 0; r < 2; ++r) {
            int u   = tid * 2 + r;               // 1024 16B-units
            int jj  = u >> 5;                    // chunk
            int ii  = (u >> 1) & 15;             // t within grp
            int hf  = u & 1;                     // which 8-channel half
            int elem = ((jj * 16 + ii) * 16 + hf * 8) ^ ((jj & 7) << 3);
            float4 v = *(const float4*)&stg[elem];
            int t = jj * 64 + grp * 16 + ii;
            *(float4*)(A + outbase + (size_t)t * C_IN_ + hf * 8) = v;
        }
    }
}

// ---------------------------------------------------------------------------
// Kernel 3: GEMM  out[m][n] = sum_k A[m][k] * W[n][k] + bias[n]
// M=65536 N=1024 K=512; 128x128 tile, BK=64, 4 waves, 4x4 16x16 frags/wave
// ---------------------------------------------------------------------------
__global__ __launch_bounds__(256)
void gemm_kernel(const bf16* __restrict__ Amat, const bf16* __restrict__ Wb,
                 const float* __restrict__ bias, float* __restrict__ out) {
    constexpr int K = C_IN_, N = D_MODEL_, BK = 64;
    __shared__ bf16 As[128 * BK];   // [m][k] 16KB
    __shared__ bf16 Bs[128 * BK];   // [n][k] 16KB
    const int tid = threadIdx.x;
    const int wid = tid >> 6, lane = tid & 63;
    const int nb = blockIdx.x & 7, mb = blockIdx.x >> 3;
    const int m0 = mb * 128, n0 = nb * 128;
    const int wr = wid >> 1, wc = wid & 1;       // wave quadrant (64x64)
    const int lrow = lane & 15, lk = (lane >> 4) * 8;

    f32x4 acc[4][4];
    #pragma unroll
    for (int i = 0; i < 4; ++i)
        #pragma unroll
        for (int q = 0; q < 4; ++q) acc[i][q] = (f32x4){0.f, 0.f, 0.f, 0.f};

    for (int kt = 0; kt < K; kt += BK) {
        const char* Ag = (const char*)(Amat + (size_t)m0 * K + kt);
        const char* Bg = (const char*)(Wb   + (size_t)n0 * K + kt);
        #pragma unroll
        for (int r = 0; r < 4; ++r) {
            int fb  = r * 4096 + tid * 16;       // flat byte in 16KB tile
            int row = fb >> 7;                   // 128B per row
            int kb  = fb & 127;
            gload16(Ag + (size_t)row * (K * 2) + kb, (char*)As + fb);
            gload16(Bg + (size_t)row * (K * 2) + kb, (char*)Bs + fb);
        }
        __syncthreads();
        #pragma unroll
        for (int ks = 0; ks < 2; ++ks) {
            short8 af[4], bff[4];
            #pragma unroll
            for (int mf = 0; mf < 4; ++mf)
                af[mf] = *(const short8*)&As[(wr * 64 + mf * 16 + lrow) * BK + ks * 32 + lk];
            #pragma unroll
            for (int nf = 0; nf < 4; ++nf)
                bff[nf] = *(const short8*)&Bs[(wc * 64 + nf * 16 + lrow) * BK + ks * 32 + lk];
            #pragma unroll
            for (int mf = 0; mf < 4; ++mf)
                #pragma unroll
                for (int nf = 0; nf < 4; ++nf)
                    acc[mf][nf] = __builtin_amdgcn_mfma_f32_16x16x32_bf16(
                        af[mf], bff[nf], acc[mf][nf], 0, 0, 0);
        }
        __syncthreads();
    }
    // epilogue: C mapping col=lane&15, row=(lane>>4)*4+reg
    #pragma unroll
    for (int mf = 0; mf < 4; ++mf) {
        #pragma unroll
        for (int nf = 0; nf < 4; ++nf) {
            int mrow0 = m0 + wr * 64 + mf * 16 + (lane >> 4) * 4;
            int ncol  = n0 + wc * 64 + nf * 16 + (lane & 15);
            float bv = bias[ncol];
            #pragma unroll
            for (int r = 0; r < 4; ++r)
                out[(size_t)(mrow0 + r) * N + ncol] = acc[mf][nf][r] + bv;
        }
    }
}

// ---------------------------------------------------------------------------
extern "C" void kernel_launch(void* const* d_in, const int* in_sizes, int n_in,
                              void* d_out, int out_size, void* d_ws, size_t ws_size,
                              hipStream_t stream) {
    const float* x    = (const float*)d_in[0];
    const float* W    = (const float*)d_in[1];
    const float* bias = (const float*)d_in[2];
    float* out = (float*)d_out;

    bf16* Wb   = (bf16*)d_ws;                          // 1MB
    bf16* Amat = (bf16*)((char*)d_ws + (1 << 21));     // 64MB at +2MB

    hipLaunchKernelGGL(wconv_kernel, dim3(512), dim3(256), 0, stream, W, Wb);
    hipLaunchKernelGGL(ewma_kernel, dim3(B_SZ * 32), dim3(512), 0, stream, x, Amat);
    hipLaunchKernelGGL(gemm_kernel, dim3((B_SZ * T_LEN / 128) * (D_MODEL_ / 128)),
                       dim3(256), 0, stream, Amat, Wb, bias, out);
}

// Round 3
// 172.637 us; speedup vs baseline: 1.1856x; 1.1856x over previous
//
#include <hip/hip_runtime.h>
#include <hip/hip_bf16.h>
#include <stdint.h>
#include <stddef.h>

#define T_LEN   2048
#define C_IN_   512
#define D_MODEL_ 1024
#define B_SZ    32

typedef __hip_bfloat16 bf16;
typedef __attribute__((ext_vector_type(8))) short short8;
typedef __attribute__((ext_vector_type(4))) float f32x4;

// ---------------------------------------------------------------------------
// async global->LDS, 16B per lane (linear dest: wave-uniform base + lane*16)
// ---------------------------------------------------------------------------
__device__ __forceinline__ void gload16(const void* g, void* l) {
    __builtin_amdgcn_global_load_lds(
        (const __attribute__((address_space(1))) uint32_t*)g,
        (__attribute__((address_space(3))) uint32_t*)l, 16, 0, 0);
}

// ---------------------------------------------------------------------------
// Kernel 1: W (fp32 [1024][512]) -> bf16, same layout
// ---------------------------------------------------------------------------
__global__ void wconv_kernel(const float* __restrict__ W, bf16* __restrict__ Wb) {
    int i = blockIdx.x * 256 + threadIdx.x;       // 131072 float4 units
    float4 v = ((const float4*)W)[i];
    bf16* o = Wb + (size_t)i * 4;
    o[0] = __float2bfloat16(v.x);
    o[1] = __float2bfloat16(v.y);
    o[2] = __float2bfloat16(v.z);
    o[3] = __float2bfloat16(v.w);
}

// ---------------------------------------------------------------------------
// Kernel 2: bidirectional EWMA, exact 3-level scan, output bf16 A[M=b*T+t][c]
// (unchanged from round 2 — at its memory floor)
// ---------------------------------------------------------------------------
__global__ __launch_bounds__(512)
void ewma_kernel(const float* __restrict__ x, bf16* __restrict__ A) {
    const int tid  = threadIdx.x;
    const int wid  = tid >> 6;          // 0..7
    const int lane = tid & 63;
    const int half = lane >> 5;         // 0,1 -> which row of the wave
    const int j    = lane & 31;         // chunk (64 t's each)
    const int b    = blockIdx.x >> 5;   // 0..31
    const int cg   = blockIdx.x & 31;   // 0..31 (16 channels per block)
    const int c_local = (wid << 1) | half;       // 0..15
    const int c    = (cg << 4) + c_local;

    const float AL = 0.1f, OM = 0.9f;
    const float Q  = 1.179018457773862e-3f;      // 0.9^64

    float xr[64];
    const float4* xp = (const float4*)(x + (size_t)(b * C_IN_ + c) * T_LEN + j * 64);
    #pragma unroll
    for (int i = 0; i < 16; ++i) {
        float4 v = xp[i];
        xr[4*i+0] = v.x; xr[4*i+1] = v.y; xr[4*i+2] = v.z; xr[4*i+3] = v.w;
    }

    float g = (j == 0) ? xr[0] : AL * xr[0];
    #pragma unroll
    for (int i = 1; i < 64; ++i) g = fmaf(OM, g, AL * xr[i]);

    float F = g, coef = Q;
    #pragma unroll
    for (int d = 1; d < 32; d <<= 1) {
        float up = __shfl_up(F, d, 32);
        F += (j >= d) ? coef * up : 0.0f;
        coef *= coef;
    }
    float carry = __shfl_up(F, 1, 32);
    if (j == 0) carry = 0.0f;

    xr[0] = (j == 0) ? xr[0] : fmaf(OM, carry, AL * xr[0]);
    #pragma unroll
    for (int i = 1; i < 64; ++i) xr[i] = fmaf(OM, xr[i-1], AL * xr[i]);

    float h;
    {
        float incL = xr[63] - OM * xr[62];
        if (j == 31) incL *= 10.0f;
        h = incL;
        #pragma unroll
        for (int i = 62; i >= 1; --i) h = fmaf(OM, h, xr[i] - OM * xr[i-1]);
        float inc0 = (j == 0) ? AL * xr[0] : (xr[0] - OM * carry);
        h = fmaf(OM, h, inc0);
    }

    float Bv = h; coef = Q;
    #pragma unroll
    for (int d = 1; d < 32; d <<= 1) {
        float dn = __shfl_down(Bv, d, 32);
        Bv += (j < 32 - d) ? coef * dn : 0.0f;
        coef *= coef;
    }
    float bnext = __shfl_down(Bv, 1, 32);
    if (j == 31) bnext = 0.0f;

    {
        float bp = bnext;
        float incL = xr[63] - OM * xr[62];
        if (j == 31) incL *= 10.0f;
        float bb = fmaf(OM, bp, incL);
        xr[63] = 0.5f * (xr[63] + bb);
        bp = bb;
        #pragma unroll
        for (int i = 62; i >= 1; --i) {
            float inc = xr[i] - OM * xr[i-1];
            bb = fmaf(OM, bp, inc);
            xr[i] = 0.5f * (xr[i] + bb);
            bp = bb;
        }
        float inc0 = (j == 0) ? AL * xr[0] : (xr[0] - OM * carry);
        bb = fmaf(OM, bp, inc0);
        xr[0] = 0.5f * (xr[0] + bb);
    }

    __shared__ bf16 stg[32 * 16 * 16];           // 16KB
    const size_t outbase = (size_t)(b * T_LEN) * C_IN_ + (cg << 4);
    #pragma unroll
    for (int grp = 0; grp < 4; ++grp) {
        __syncthreads();
        #pragma unroll
        for (int ii = 0; ii < 16; ++ii) {
            int elem = ((j * 16 + ii) * 16 + c_local) ^ ((j & 7) << 3);
            stg[elem] = __float2bfloat16(xr[grp * 16 + ii]);
        }
        __syncthreads();
        #pragma unroll
        for (int r = 0; r < 2; ++r) {
            int u   = tid * 2 + r;               // 1024 16B-units
            int jj  = u >> 5;
            int ii  = (u >> 1) & 15;
            int hf  = u & 1;
            int elem = ((jj * 16 + ii) * 16 + hf * 8) ^ ((jj & 7) << 3);
            float4 v = *(const float4*)&stg[elem];
            int t = jj * 64 + grp * 16 + ii;
            *(float4*)(A + outbase + (size_t)t * C_IN_ + hf * 8) = v;
        }
    }
}

// ---------------------------------------------------------------------------
// Kernel 3: GEMM  out[m][n] = sum_k A[m][k]*W[n][k] + bias[n]
// 256x256 tile, BK=64, 8 waves (2Mx4N), 8-phase schedule (T1+T2+T3+T4+T5).
// LDS 128KB dynamic: [set:2][op A/B:2][half:2][128 rows][8 units of 16B],
// swizzle: physical unit = logical unit ^ (row&7)   (involution, both sides)
// ---------------------------------------------------------------------------
#define MFMA(a, b, c) __builtin_amdgcn_mfma_f32_16x16x32_bf16(a, b, c, 0, 0, 0)

__global__ __launch_bounds__(512)
void gemm_kernel(const bf16* __restrict__ Amat, const bf16* __restrict__ Wb,
                 const float* __restrict__ bias, float* __restrict__ out) {
    constexpr int K = C_IN_, N = D_MODEL_;
    extern __shared__ bf16 lds[];                // 2*2*2*8192 bf16 = 128 KB
    const int tid  = threadIdx.x;
    const int wid  = tid >> 6, lane = tid & 63;
    const int wr   = wid >> 2, wc = wid & 3;     // 2 x 4 wave grid
    const int lr   = lane & 15;                  // frag row/col
    const int lg   = lane >> 4;                  // k-group 0..3

    // T1: bijective XCD swizzle (1024 blocks, 1024%8==0)
    int bid = blockIdx.x;
    int swz = (bid & 7) * 128 + (bid >> 3);
    const int mb = swz >> 2, nb = swz & 3;
    const int m0 = mb * 256, n0 = nb * 256;

    auto base = [&](int s, int op, int hf) -> bf16* {
        return lds + (((s * 2 + op) * 2 + hf) << 13);
    };
    // stage one 16KB half-tile (128 rows x 64 k) : linear LDS dest,
    // inverse-swizzled global source (rule #21)
    auto stage = [&](const bf16* g, int row0, int kt, int s, int op, int hf) {
        bf16* lb = base(s, op, hf);
        #pragma unroll
        for (int r = 0; r < 2; ++r) {
            int q = tid + r * 512;
            int row = q >> 3, u = q & 7;
            gload16(g + (size_t)(row0 + row) * K + kt * 64 + ((u ^ (row & 7)) << 3),
                    (char*)lb + q * 16);
        }
    };
    auto rdA = [&](int s, int mf, int ks) -> short8 {
        int row = mf * 16 + lr;
        int u   = ks * 4 + lg;
        return *(const short8*)((const char*)base(s, 0, wr)
                                + row * 128 + ((u ^ (row & 7)) << 4));
    };
    auto rdB = [&](int s, int nf, int ks) -> short8 {
        int row = (wc & 1) * 64 + nf * 16 + lr;
        int u   = ks * 4 + lg;
        return *(const short8*)((const char*)base(s, 1, wc >> 1)
                                + row * 128 + ((u ^ (row & 7)) << 4));
    };

    f32x4 acc[8][4];
    #pragma unroll
    for (int m = 0; m < 8; ++m)
        #pragma unroll
        for (int n = 0; n < 4; ++n) acc[m][n] = (f32x4){0.f, 0.f, 0.f, 0.f};

    // ---- prologue: kt0 full (set0) + A0 of kt1 (set1); wait kt0, keep 2 in flight
    stage(Amat, m0 + 0,   0, 0, 0, 0);
    stage(Amat, m0 + 128, 0, 0, 0, 1);
    stage(Wb,   n0 + 0,   0, 0, 1, 0);
    stage(Wb,   n0 + 128, 0, 0, 1, 1);
    stage(Amat, m0 + 0,   1, 1, 0, 0);
    asm volatile("s_waitcnt vmcnt(2)" ::: "memory");
    __builtin_amdgcn_s_barrier();

    // ---- K loop: 8 K-tiles, 4 phases each
    #pragma unroll
    for (int kt = 0; kt < 8; ++kt) {
        const int s = kt & 1;
        short8 a[4][2], bA[2][2], bB[2][2];

        // phase 1: read A0-3 + B0-1 ; stage A1(kt+1)
        #pragma unroll
        for (int m = 0; m < 4; ++m) { a[m][0] = rdA(s, m, 0); a[m][1] = rdA(s, m, 1); }
        #pragma unroll
        for (int n = 0; n < 2; ++n) { bA[n][0] = rdB(s, n, 0); bA[n][1] = rdB(s, n, 1); }
        if (kt < 7) stage(Amat, m0 + 128, kt + 1, s ^ 1, 0, 1);
        __builtin_amdgcn_s_barrier();
        asm volatile("s_waitcnt lgkmcnt(0)");
        __builtin_amdgcn_sched_barrier(0);
        __builtin_amdgcn_s_setprio(1);
        #pragma unroll
        for (int m = 0; m < 4; ++m)
            #pragma unroll
            for (int n = 0; n < 2; ++n) {
                acc[m][n] = MFMA(a[m][0], bA[n][0], acc[m][n]);
                acc[m][n] = MFMA(a[m][1], bA[n][1], acc[m][n]);
            }
        __builtin_amdgcn_s_setprio(0);
        __builtin_amdgcn_s_barrier();

        // phase 2: read B2-3 ; stage B0(kt+1)
        #pragma unroll
        for (int n = 0; n < 2; ++n) { bB[n][0] = rdB(s, 2 + n, 0); bB[n][1] = rdB(s, 2 + n, 1); }
        if (kt < 7) stage(Wb, n0 + 0, kt + 1, s ^ 1, 1, 0);
        __builtin_amdgcn_s_barrier();
        asm volatile("s_waitcnt lgkmcnt(0)");
        __builtin_amdgcn_sched_barrier(0);
        __builtin_amdgcn_s_setprio(1);
        #pragma unroll
        for (int m = 0; m < 4; ++m)
            #pragma unroll
            for (int n = 0; n < 2; ++n) {
                acc[m][2 + n] = MFMA(a[m][0], bB[n][0], acc[m][2 + n]);
                acc[m][2 + n] = MFMA(a[m][1], bB[n][1], acc[m][2 + n]);
            }
        __builtin_amdgcn_s_setprio(0);
        __builtin_amdgcn_s_barrier();

        // phase 3: read A4-7 (reuse regs) ; stage B1(kt+1)
        #pragma unroll
        for (int m = 0; m < 4; ++m) { a[m][0] = rdA(s, 4 + m, 0); a[m][1] = rdA(s, 4 + m, 1); }
        if (kt < 7) stage(Wb, n0 + 128, kt + 1, s ^ 1, 1, 1);
        __builtin_amdgcn_s_barrier();
        asm volatile("s_waitcnt lgkmcnt(0)");
        __builtin_amdgcn_sched_barrier(0);
        __builtin_amdgcn_s_setprio(1);
        #pragma unroll
        for (int m = 0; m < 4; ++m)
            #pragma unroll
            for (int n = 0; n < 2; ++n) {
                acc[4 + m][2 + n] = MFMA(a[m][0], bB[n][0], acc[4 + m][2 + n]);
                acc[4 + m][2 + n] = MFMA(a[m][1], bB[n][1], acc[4 + m][2 + n]);
            }
        __builtin_amdgcn_s_setprio(0);
        __builtin_amdgcn_s_barrier();

        // phase 4: stage A0(kt+2) into set s (free since end of phase 3);
        //          MFMA m4-7 x n0-1 (bA live since phase 1); counted vmcnt
        if (kt < 6) stage(Amat, m0 + 0, kt + 2, s, 0, 0);
        __builtin_amdgcn_s_setprio(1);
        #pragma unroll
        for (int m = 0; m < 4; ++m)
            #pragma unroll
            for (int n = 0; n < 2; ++n) {
                acc[4 + m][n] = MFMA(a[m][0], bA[n][0], acc[4 + m][n]);
                acc[4 + m][n] = MFMA(a[m][1], bA[n][1], acc[4 + m][n]);
            }
        __builtin_amdgcn_s_setprio(0);
        if (kt < 6)       asm volatile("s_waitcnt vmcnt(2)" ::: "memory");
        else if (kt == 6) asm volatile("s_waitcnt vmcnt(0)" ::: "memory");
        __builtin_amdgcn_s_barrier();
    }

    // ---- epilogue: C write + bias (fp32)
    const int crow = (lane >> 4) << 2;
    #pragma unroll
    for (int nf = 0; nf < 4; ++nf) {
        int col = n0 + wc * 64 + nf * 16 + lr;
        float bv = bias[col];
        #pragma unroll
        for (int mf = 0; mf < 8; ++mf) {
            size_t rbase = (size_t)(m0 + wr * 128 + mf * 16 + crow) * N + col;
            #pragma unroll
            for (int r = 0; r < 4; ++r)
                out[rbase + (size_t)r * N] = acc[mf][nf][r] + bv;
        }
    }
}

// ---------------------------------------------------------------------------
extern "C" void kernel_launch(void* const* d_in, const int* in_sizes, int n_in,
                              void* d_out, int out_size, void* d_ws, size_t ws_size,
                              hipStream_t stream) {
    const float* x    = (const float*)d_in[0];
    const float* W    = (const float*)d_in[1];
    const float* bias = (const float*)d_in[2];
    float* out = (float*)d_out;

    bf16* Wb   = (bf16*)d_ws;                          // 1MB
    bf16* Amat = (bf16*)((char*)d_ws + (1 << 21));     // 64MB at +2MB

    hipLaunchKernelGGL(wconv_kernel, dim3(512), dim3(256), 0, stream, W, Wb);
    hipLaunchKernelGGL(ewma_kernel, dim3(B_SZ * 32), dim3(512), 0, stream, x, Amat);
    hipLaunchKernelGGL(gemm_kernel,
                       dim3((B_SZ * T_LEN / 256) * (D_MODEL_ / 256)),
                       dim3(512), 131072, stream, Amat, Wb, bias, out);
}